// Round 1
// baseline (1664.786 us; speedup 1.0000x reference)
//
#include <hip/hip_runtime.h>
#include <hip/hip_bf16.h>

#define BATCH 131072
#define H 256
#define NBLK 8
#define NMID 3
#define MS 32            // samples per workgroup
#define RT_N 6           // (3 streams * MS) / 16 row-tiles
#define NT 256           // threads per workgroup

typedef __attribute__((ext_vector_type(8))) short short8;   // 8 bf16 = 4 VGPRs (MFMA A/B frag)
typedef __attribute__((ext_vector_type(4))) float f32x4;    // MFMA C/D frag

// pack two f32 -> two bf16 (round-half-up) in 3 VALU ops: 2 adds + v_perm.
// low16 = bf(a), high16 = bf(b)  (matches (bf(a) | bf(b)<<16))
__device__ __forceinline__ unsigned pk2(float a, float b) {
    unsigned ua = __float_as_uint(a) + 0x8000u;
    unsigned ub = __float_as_uint(b) + 0x8000u;
    return __builtin_amdgcn_perm(ub, ua, 0x07060302u);
}
__device__ __forceinline__ unsigned short f2bf(float f) {
    return (unsigned short)((__float_as_uint(f) + 0x8000u) >> 16);
}

// Pack Wm into MFMA B-frag order bf16 with COLUMN-PERMUTED tiles:
// tile T = wave*4+ct covers physical cols n = (T>>2)*64 + m*4 + (T&3), m = lane&15.
// => in the epilogue each thread owns 4 consecutive columns (one ds_write_b64).
__global__ void pack_w_kernel(const float* __restrict__ Wm, unsigned short* __restrict__ Wp) {
    int o = blockIdx.x * blockDim.x + threadIdx.x;   // 24 * 8192 chunks
    if (o >= NBLK * NMID * 8192) return;
    int lane  = o & 63;
    int T     = (o >> 6) & 15;
    int kk    = (o >> 10) & 7;
    int layer = o >> 13;
    int n  = (T >> 2) * 64 + (lane & 15) * 4 + (T & 3);
    int k0 = kk * 32 + (lane >> 4) * 8;
    const float* src = Wm + (size_t)layer * H * H;
    unsigned int w[4];
    #pragma unroll
    for (int jj = 0; jj < 4; ++jj)
        w[jj] = pk2(src[(size_t)(k0 + 2*jj) * H + n], src[(size_t)(k0 + 2*jj + 1) * H + n]);
    uint4 val; val.x = w[0]; val.y = w[1]; val.z = w[2]; val.w = w[3];
    ((uint4*)Wp)[o] = val;
}

// bias+ReLU on primal, mask tangents, write next layer's A-frag X (b64 stores).
__device__ __forceinline__ void epilogue_write(const f32x4 (&acc)[RT_N][4],
                                               const float* __restrict__ bias,
                                               unsigned short* __restrict__ Xs,
                                               int wave, int lane) {
    const int mcol = lane & 15, quad = lane >> 4;
    const int nb = wave * 64 + mcol * 4;           // 4 consecutive output cols
    const float4 bv = *(const float4*)(bias + nb);
    const int kkx = nb >> 5;
    const int qx  = (nb >> 3) & 3;
    const int jb  = nb & 7;                        // 0 or 4
    #pragma unroll
    for (int g = 0; g < 2; ++g) {
        #pragma unroll
        for (int r = 0; r < 4; ++r) {
            float pre[4], hv[4], ta[4], tb[4];
            pre[0] = acc[g][0][r] + bv.x; pre[1] = acc[g][1][r] + bv.y;
            pre[2] = acc[g][2][r] + bv.z; pre[3] = acc[g][3][r] + bv.w;
            #pragma unroll
            for (int c = 0; c < 4; ++c) {
                bool mk = pre[c] > 0.0f;
                hv[c] = mk ? pre[c]        : 0.0f;
                ta[c] = mk ? acc[2+g][c][r] : 0.0f;
                tb[c] = mk ? acc[4+g][c][r] : 0.0f;
            }
            int rowm = quad * 4 + r;
            int le   = qx * 16 + rowm;
            int scl  = le ^ ((le >> 3) & 7);
            int e0   = (((g * 8 + kkx) * 64 + scl) * 8) + jb;
            uint2 ph; ph.x = pk2(hv[0], hv[1]); ph.y = pk2(hv[2], hv[3]);
            uint2 pa; pa.x = pk2(ta[0], ta[1]); pa.y = pk2(ta[2], ta[3]);
            uint2 pb; pb.x = pk2(tb[0], tb[1]); pb.y = pk2(tb[2], tb[3]);
            *(uint2*)(Xs + e0)          = ph;
            *(uint2*)(Xs + e0 + 8192)   = pa;   // ta rows: rt offset +2 => +2*8*64*8 elems
            *(uint2*)(Xs + e0 + 16384)  = pb;   // tb rows: rt offset +4
        }
    }
}

__global__ __launch_bounds__(NT, 3)
void flow_kernel(const float* __restrict__ x, const float* __restrict__ v,
                 const float* __restrict__ Wi, const float* __restrict__ bi,
                 const float* __restrict__ bm, const float* __restrict__ Wo,
                 const float* __restrict__ bo,
                 const unsigned short* __restrict__ Wp,
                 float* __restrict__ out)
{
    __shared__ uint4 Xl4[RT_N * 8 * 64];     // 3072 chunks * 16B = 48 KiB
    __shared__ float zbuf[MS * 2];
    __shared__ float vbuf[MS * 2];

    unsigned short* Xs = (unsigned short*)Xl4;

    const int tid  = threadIdx.x;
    const int wave = tid >> 6;
    const int lane = tid & 63;
    const int mcol = lane & 15;
    const int quad = lane >> 4;
    const int s0   = blockIdx.x * MS;
    const int rl   = lane ^ ((lane >> 3) & 7);   // swizzled A-read slot

    float dlp = 0.0f;
    if (tid < MS) {
        zbuf[tid*2+0] = x[(size_t)(s0+tid)*2+0];
        zbuf[tid*2+1] = x[(size_t)(s0+tid)*2+1];
        vbuf[tid*2+0] = v[(size_t)(s0+tid)*2+0];
        vbuf[tid*2+1] = v[(size_t)(s0+tid)*2+1];
    }

    // Phase-stagger co-resident WGs: they are fully data-independent, so a
    // one-time skew of ~1/3 mid-layer per slot decorrelates MFMA vs
    // epilogue/barrier phases for the rest of the kernel. Co-resident WGs
    // are ~256-768 apart in dispatch order -> distinct (bid>>8)%3 slots.
    {
        const int slot = (blockIdx.x >> 8) % 3;
        for (int i = 0; i < slot * 5; ++i) __builtin_amdgcn_s_sleep(8);
    }
    __syncthreads();

    for (int b = 0; b < NBLK; ++b) {
        // ------------- layer 0: 2 -> 256 via MFMA (K padded to 32) -------------
        // Fill X0: rows 96 x K32, chunks at (rt*8+0)*64 + slot; only q==0,j<2 nonzero.
        #pragma unroll
        for (int cc = 0; cc < 2; ++cc) {
            int c = cc * NT + tid;
            if (c < 384) {
                int rt = c >> 6, cl = c & 63;
                int l = cl ^ ((cl >> 3) & 7);
                int m = l & 15, q = l >> 4;
                int st = rt >> 1;
                uint4 pk = {0u, 0u, 0u, 0u};
                if (q == 0) {
                    if (st == 0) {
                        int s = ((rt & 1) << 4) | m;
                        pk.x = pk2(zbuf[s*2+0], zbuf[s*2+1]);
                    } else if (st == 1) pk.x = 0x00003F80u;   // (1,0)
                    else                pk.x = 0x3F800000u;   // (0,1)
                }
                Xl4[rt * 512 + cl] = pk;
            }
        }
        __syncthreads();

        const float* Wi0 = Wi + (size_t)b * 2 * H;
        const float* Wi1 = Wi0 + H;
        {
            short8 b0[4];
            #pragma unroll
            for (int ct = 0; ct < 4; ++ct) {
                short8 z = {0,0,0,0,0,0,0,0};
                if (lane < 16) {
                    int n = wave * 64 + lane * 4 + ct;
                    unsigned p = pk2(Wi0[n], Wi1[n]);
                    z[0] = (short)(p & 0xFFFFu);
                    z[1] = (short)(p >> 16);
                }
                b0[ct] = z;
            }
            f32x4 acc[RT_N][4];
            #pragma unroll
            for (int rt = 0; rt < RT_N; ++rt)
                #pragma unroll
                for (int ct = 0; ct < 4; ++ct)
                    acc[rt][ct] = (f32x4){0.f, 0.f, 0.f, 0.f};
            #pragma unroll
            for (int rt = 0; rt < RT_N; ++rt) {
                short8 af = ((const short8*)Xl4)[(rt * 8) * 64 + rl];
                #pragma unroll
                for (int ct = 0; ct < 4; ++ct)
                    acc[rt][ct] = __builtin_amdgcn_mfma_f32_16x16x32_bf16(af, b0[ct], acc[rt][ct], 0, 0, 0);
            }
            __syncthreads();                     // X0 reads done
            epilogue_write(acc, bi + (size_t)b * H, Xs, wave, lane);
            __syncthreads();
        }

        // ------------- mid layers: 3x (256 -> 256) via MFMA -------------
        for (int li = 0; li < NMID; ++li) {
            const int layer = b * NMID + li;
            const short8* Bp  = ((const short8*)Wp) + (size_t)layer * 8192;
            const float* bias = bm + (size_t)layer * H;

            f32x4 acc[RT_N][4];
            #pragma unroll
            for (int rt = 0; rt < RT_N; ++rt)
                #pragma unroll
                for (int ct = 0; ct < 4; ++ct)
                    acc[rt][ct] = (f32x4){0.f, 0.f, 0.f, 0.f};

            #pragma unroll
            for (int kk = 0; kk < 8; ++kk) {
                short8 bf[4];
                #pragma unroll
                for (int ct = 0; ct < 4; ++ct)
                    bf[ct] = Bp[(kk*16 + wave*4 + ct)*64 + lane];        // coalesced b128 (L2-hot)
                #pragma unroll
                for (int rt = 0; rt < RT_N; ++rt) {
                    short8 af = ((const short8*)Xl4)[(rt*8 + kk)*64 + rl]; // ds_read_b128
                    #pragma unroll
                    for (int ct = 0; ct < 4; ++ct)
                        acc[rt][ct] = __builtin_amdgcn_mfma_f32_16x16x32_bf16(af, bf[ct], acc[rt][ct], 0, 0, 0);
                }
            }
            __syncthreads();                     // all waves done reading X
            epilogue_write(acc, bias, Xs, wave, lane);
            __syncthreads();
        }

        // ------------- layer 4: 256 -> 2 via MFMA (N padded to 16) -------------
        const float* Wob = Wo + (size_t)b * H * 2;
        const float* bob = bo + (size_t)b * 2;
        {
            short8 b4[2];
            #pragma unroll
            for (int kki = 0; kki < 2; ++kki) {
                short8 z = {0,0,0,0,0,0,0,0};
                if (mcol < 2) {
                    int kb = (wave * 2 + kki) * 32 + quad * 8;
                    #pragma unroll
                    for (int jj = 0; jj < 4; ++jj) {
                        unsigned p = pk2(Wob[(kb + 2*jj) * 2 + mcol], Wob[(kb + 2*jj + 1) * 2 + mcol]);
                        z[2*jj]   = (short)(p & 0xFFFFu);
                        z[2*jj+1] = (short)(p >> 16);
                    }
                }
                b4[kki] = z;
            }
            f32x4 accL[RT_N];
            #pragma unroll
            for (int rt = 0; rt < RT_N; ++rt) accL[rt] = (f32x4){0.f, 0.f, 0.f, 0.f};
            #pragma unroll
            for (int rt = 0; rt < RT_N; ++rt) {
                short8 a0 = ((const short8*)Xl4)[(rt*8 + wave*2    )*64 + rl];
                accL[rt] = __builtin_amdgcn_mfma_f32_16x16x32_bf16(a0, b4[0], accL[rt], 0, 0, 0);
                short8 a1 = ((const short8*)Xl4)[(rt*8 + wave*2 + 1)*64 + rl];
                accL[rt] = __builtin_amdgcn_mfma_f32_16x16x32_bf16(a1, b4[1], accL[rt], 0, 0, 0);
            }
            __syncthreads();                     // X dead; overlay partials
            float* part = (float*)Xl4;           // 768 floats
            if (mcol < 2) {
                #pragma unroll
                for (int rt = 0; rt < RT_N; ++rt)
                    #pragma unroll
                    for (int r = 0; r < 4; ++r)
                        part[((rt*16 + quad*4 + r)*2 + mcol)*4 + wave] = accL[rt][r];
            }
            __syncthreads();
            float* res = part + 768;             // 192 floats
            if (tid < 192) {
                float4 p4 = ((const float4*)part)[tid];
                res[tid] = p4.x + p4.y + p4.z + p4.w;
            }
            __syncthreads();
            if (tid < MS) {
                int g = tid >> 4, row = tid & 15;
                // res index: ((st*2+g)*16 + row)*2 + m
                int base = (g * 16 + row) * 2;
                float SH0 = res[base], SH1 = res[base + 1];
                float SA0 = res[base + 64], SA1 = res[base + 65];   // st=1: +2*16*2
                float SB0 = res[base + 128], SB1 = res[base + 129]; // st=2
                float pre0 = SH0 + bob[0], pre1 = SH1 + bob[1];
                bool  m0 = pre0 > 0.f,     m1 = pre1 > 0.f;
                float gx0 = m0 ? pre0 : 0.f, gx1 = m1 ? pre1 : 0.f;
                float J00 = m0 ? SA0 : 0.f;
                float J01 = m0 ? SB0 : 0.f;
                float J10 = m1 ? SA1 : 0.f;
                float J11 = m1 ? SB1 : 0.f;
                float v0 = vbuf[tid*2+0], v1 = vbuf[tid*2+1];
                float w0 = v0, w1 = v1, ld = 0.f;
                const float coef[5] = {1.f, -0.5f, 1.f/3.f, -0.25f, 0.2f};
                #pragma unroll
                for (int k = 0; k < 5; ++k) {
                    float nw0 = fmaf(J00, w0, J01 * w1);
                    float nw1 = fmaf(J10, w0, J11 * w1);
                    w0 = nw0; w1 = nw1;
                    ld = fmaf(coef[k], fmaf(w0, v0, w1 * v1), ld);
                }
                zbuf[tid*2+0] += gx0;
                zbuf[tid*2+1] += gx1;
                dlp -= ld;
            }
        }
        __syncthreads();
    }

    if (tid < MS) {
        out[(size_t)(s0+tid)*2+0] = zbuf[tid*2+0];
        out[(size_t)(s0+tid)*2+1] = zbuf[tid*2+1];
        out[(size_t)2*BATCH + s0 + tid] = dlp;
    }
}

extern "C" void kernel_launch(void* const* d_in, const int* in_sizes, int n_in,
                              void* d_out, int out_size, void* d_ws, size_t ws_size,
                              hipStream_t stream) {
    const float* x  = (const float*)d_in[0];
    const float* v  = (const float*)d_in[1];
    const float* Wi = (const float*)d_in[2];
    const float* bi = (const float*)d_in[3];
    const float* Wm = (const float*)d_in[4];
    const float* bm = (const float*)d_in[5];
    const float* Wo = (const float*)d_in[6];
    const float* bo = (const float*)d_in[7];
    unsigned short* Wp = (unsigned short*)d_ws;   // 24*65536*2 = 3 MiB

    int nchunks = NBLK * NMID * 8192;
    pack_w_kernel<<<(nchunks + 255) / 256, 256, 0, stream>>>(Wm, Wp);
    flow_kernel<<<BATCH / MS, NT, 0, stream>>>(x, v, Wi, bi, bm, Wo, bo, Wp, (float*)d_out);
}

// Round 2
// 1300.549 us; speedup vs baseline: 1.2801x; 1.2801x over previous
//
#include <hip/hip_runtime.h>
#include <hip/hip_bf16.h>

#define BATCH 131072
#define H 256
#define NBLK 8
#define NMID 3
#define MS 32            // samples per workgroup
#define RT_N 6           // (3 streams * MS) / 16 row-tiles
#define NT 256           // threads per workgroup

typedef __attribute__((ext_vector_type(8))) short short8;   // 8 bf16 = 4 VGPRs (MFMA A/B frag)
typedef __attribute__((ext_vector_type(4))) float f32x4;    // MFMA C/D frag

// pack two f32 -> two bf16 (round-half-up) in 3 VALU ops: 2 adds + v_perm.
// low16 = bf(a), high16 = bf(b)  (matches (bf(a) | bf(b)<<16))
__device__ __forceinline__ unsigned pk2(float a, float b) {
    unsigned ua = __float_as_uint(a) + 0x8000u;
    unsigned ub = __float_as_uint(b) + 0x8000u;
    return __builtin_amdgcn_perm(ub, ua, 0x07060302u);
}
__device__ __forceinline__ unsigned short f2bf(float f) {
    return (unsigned short)((__float_as_uint(f) + 0x8000u) >> 16);
}

// Pack Wm into MFMA B-frag order bf16 with COLUMN-PERMUTED tiles:
// tile T = wave*4+ct covers physical cols n = (T>>2)*64 + m*4 + (T&3), m = lane&15.
// => in the epilogue each thread owns 4 consecutive columns (one ds_write_b64).
// ODD-kk K-PERM (bank-conflict fix): for odd kk the X chunks store their two
// 8B halves swapped (k -> k^4 within the K=32 block). Compensate here by
// loading uint pair jj from k-group jj^2.
__global__ void pack_w_kernel(const float* __restrict__ Wm, unsigned short* __restrict__ Wp) {
    int o = blockIdx.x * blockDim.x + threadIdx.x;   // 24 * 8192 chunks
    if (o >= NBLK * NMID * 8192) return;
    int lane  = o & 63;
    int T     = (o >> 6) & 15;
    int kk    = (o >> 10) & 7;
    int layer = o >> 13;
    int n  = (T >> 2) * 64 + (lane & 15) * 4 + (T & 3);
    int k0 = kk * 32 + (lane >> 4) * 8;
    const float* src = Wm + (size_t)layer * H * H;
    const int sw = (kk & 1) << 1;                    // swap uint pairs for odd kk
    unsigned int w[4];
    #pragma unroll
    for (int jj = 0; jj < 4; ++jj) {
        int jq = jj ^ sw;
        w[jj] = pk2(src[(size_t)(k0 + 2*jq) * H + n], src[(size_t)(k0 + 2*jq + 1) * H + n]);
    }
    uint4 val; val.x = w[0]; val.y = w[1]; val.z = w[2]; val.w = w[3];
    ((uint4*)Wp)[o] = val;
}

// bias+ReLU on primal, mask tangents, write next layer's A-frag X (b64 stores).
// Odd-kkx chunks get their 8B halves swapped (jb ^= 4) so that lanes mcol and
// mcol+8 (which share banks: +1024B = same banks mod 32) land on disjoint
// bank-pairs -> write conflicts drop 4-way -> 2-way (free).
__device__ __forceinline__ void epilogue_write(const f32x4 (&acc)[RT_N][4],
                                               const float* __restrict__ bias,
                                               unsigned short* __restrict__ Xs,
                                               int wave, int lane) {
    const int mcol = lane & 15, quad = lane >> 4;
    const int nb = wave * 64 + mcol * 4;           // 4 consecutive output cols
    const float4 bv = *(const float4*)(bias + nb);
    const int kkx = nb >> 5;
    const int qx  = (nb >> 3) & 3;
    const int jb  = (nb & 7) ^ ((kkx & 1) << 2);   // 0 or 4, halves swapped for odd kk
    #pragma unroll
    for (int g = 0; g < 2; ++g) {
        #pragma unroll
        for (int r = 0; r < 4; ++r) {
            float pre[4], hv[4], ta[4], tb[4];
            pre[0] = acc[g][0][r] + bv.x; pre[1] = acc[g][1][r] + bv.y;
            pre[2] = acc[g][2][r] + bv.z; pre[3] = acc[g][3][r] + bv.w;
            #pragma unroll
            for (int c = 0; c < 4; ++c) {
                bool mk = pre[c] > 0.0f;
                hv[c] = mk ? pre[c]        : 0.0f;
                ta[c] = mk ? acc[2+g][c][r] : 0.0f;
                tb[c] = mk ? acc[4+g][c][r] : 0.0f;
            }
            int rowm = quad * 4 + r;
            int le   = qx * 16 + rowm;
            int scl  = le ^ ((le >> 3) & 7);
            int e0   = (((g * 8 + kkx) * 64 + scl) * 8) + jb;
            uint2 ph; ph.x = pk2(hv[0], hv[1]); ph.y = pk2(hv[2], hv[3]);
            uint2 pa; pa.x = pk2(ta[0], ta[1]); pa.y = pk2(ta[2], ta[3]);
            uint2 pb; pb.x = pk2(tb[0], tb[1]); pb.y = pk2(tb[2], tb[3]);
            *(uint2*)(Xs + e0)          = ph;
            *(uint2*)(Xs + e0 + 8192)   = pa;   // ta rows: rt offset +2 => +2*8*64*8 elems
            *(uint2*)(Xs + e0 + 16384)  = pb;   // tb rows: rt offset +4
        }
    }
}

__global__ __launch_bounds__(NT, 2)
void flow_kernel(const float* __restrict__ x, const float* __restrict__ v,
                 const float* __restrict__ Wi, const float* __restrict__ bi,
                 const float* __restrict__ bm, const float* __restrict__ Wo,
                 const float* __restrict__ bo,
                 const unsigned short* __restrict__ Wp,
                 float* __restrict__ out)
{
    __shared__ uint4 Xl4[RT_N * 8 * 64];     // 3072 chunks * 16B = 48 KiB
    __shared__ float zbuf[MS * 2];
    __shared__ float vbuf[MS * 2];

    unsigned short* Xs = (unsigned short*)Xl4;

    const int tid  = threadIdx.x;
    const int wave = tid >> 6;
    const int lane = tid & 63;
    const int mcol = lane & 15;
    const int quad = lane >> 4;
    const int s0   = blockIdx.x * MS;
    const int rl   = lane ^ ((lane >> 3) & 7);   // swizzled A-read slot

    float dlp = 0.0f;
    if (tid < MS) {
        zbuf[tid*2+0] = x[(size_t)(s0+tid)*2+0];
        zbuf[tid*2+1] = x[(size_t)(s0+tid)*2+1];
        vbuf[tid*2+0] = v[(size_t)(s0+tid)*2+0];
        vbuf[tid*2+1] = v[(size_t)(s0+tid)*2+1];
    }

    // Phase-stagger co-resident WGs (data-independent): one-time skew
    // decorrelates MFMA vs epilogue phases of the 2 resident WGs.
    {
        const int slot = (blockIdx.x >> 8) % 3;
        for (int i = 0; i < slot * 5; ++i) __builtin_amdgcn_s_sleep(8);
    }
    __syncthreads();

    for (int b = 0; b < NBLK; ++b) {
        // ------------- layer 0: 2 -> 256 via MFMA (K padded to 32) -------------
        // Fill X0: rows 96 x K32, chunks at (rt*8+0)*64 + slot; only q==0,j<2 nonzero.
        // kk=0 (even) only -> no half-swap here.
        #pragma unroll
        for (int cc = 0; cc < 2; ++cc) {
            int c = cc * NT + tid;
            if (c < 384) {
                int rt = c >> 6, cl = c & 63;
                int l = cl ^ ((cl >> 3) & 7);
                int m = l & 15, q = l >> 4;
                int st = rt >> 1;
                uint4 pk = {0u, 0u, 0u, 0u};
                if (q == 0) {
                    if (st == 0) {
                        int s = ((rt & 1) << 4) | m;
                        pk.x = pk2(zbuf[s*2+0], zbuf[s*2+1]);
                    } else if (st == 1) pk.x = 0x00003F80u;   // (1,0)
                    else                pk.x = 0x3F800000u;   // (0,1)
                }
                Xl4[rt * 512 + cl] = pk;
            }
        }
        __syncthreads();

        const float* Wi0 = Wi + (size_t)b * 2 * H;
        const float* Wi1 = Wi0 + H;
        {
            short8 b0[4];
            #pragma unroll
            for (int ct = 0; ct < 4; ++ct) {
                short8 z = {0,0,0,0,0,0,0,0};
                if (lane < 16) {
                    int n = wave * 64 + lane * 4 + ct;
                    unsigned p = pk2(Wi0[n], Wi1[n]);
                    z[0] = (short)(p & 0xFFFFu);
                    z[1] = (short)(p >> 16);
                }
                b0[ct] = z;
            }
            f32x4 acc[RT_N][4];
            #pragma unroll
            for (int rt = 0; rt < RT_N; ++rt)
                #pragma unroll
                for (int ct = 0; ct < 4; ++ct)
                    acc[rt][ct] = (f32x4){0.f, 0.f, 0.f, 0.f};
            #pragma unroll
            for (int rt = 0; rt < RT_N; ++rt) {
                short8 af = ((const short8*)Xl4)[(rt * 8) * 64 + rl];
                #pragma unroll
                for (int ct = 0; ct < 4; ++ct)
                    acc[rt][ct] = __builtin_amdgcn_mfma_f32_16x16x32_bf16(af, b0[ct], acc[rt][ct], 0, 0, 0);
            }
            __syncthreads();                     // X0 reads done
            epilogue_write(acc, bi + (size_t)b * H, Xs, wave, lane);
            __syncthreads();
        }

        // ------------- mid layers: 3x (256 -> 256) via MFMA -------------
        for (int li = 0; li < NMID; ++li) {
            const int layer = b * NMID + li;
            const short8* Bp  = ((const short8*)Wp) + (size_t)layer * 8192;
            const float* bias = bm + (size_t)layer * H;

            f32x4 acc[RT_N][4];
            #pragma unroll
            for (int rt = 0; rt < RT_N; ++rt)
                #pragma unroll
                for (int ct = 0; ct < 4; ++ct)
                    acc[rt][ct] = (f32x4){0.f, 0.f, 0.f, 0.f};

            __builtin_amdgcn_s_setprio(1);       // favor this wave's MFMA cluster
            #pragma unroll
            for (int kk = 0; kk < 8; ++kk) {
                short8 bf[4];
                #pragma unroll
                for (int ct = 0; ct < 4; ++ct)
                    bf[ct] = Bp[(kk*16 + wave*4 + ct)*64 + lane];        // coalesced b128 (L2-hot)
                #pragma unroll
                for (int rt = 0; rt < RT_N; ++rt) {
                    short8 af = ((const short8*)Xl4)[(rt*8 + kk)*64 + rl]; // ds_read_b128
                    #pragma unroll
                    for (int ct = 0; ct < 4; ++ct)
                        acc[rt][ct] = __builtin_amdgcn_mfma_f32_16x16x32_bf16(af, bf[ct], acc[rt][ct], 0, 0, 0);
                }
            }
            __builtin_amdgcn_s_setprio(0);
            __syncthreads();                     // all waves done reading X
            epilogue_write(acc, bias, Xs, wave, lane);
            __syncthreads();
        }

        // ------------- layer 4: 256 -> 2 via MFMA (N padded to 16) -------------
        const float* Wob = Wo + (size_t)b * H * 2;
        const float* bob = bo + (size_t)b * 2;
        {
            short8 b4[2];
            #pragma unroll
            for (int kki = 0; kki < 2; ++kki) {
                short8 z = {0,0,0,0,0,0,0,0};
                const int kkg = wave * 2 + kki;
                const int sw  = (kkg & 1) << 1;          // compensate odd-kk half-swap
                if (mcol < 2) {
                    int kb = kkg * 32 + quad * 8;
                    #pragma unroll
                    for (int jj = 0; jj < 4; ++jj) {
                        int jq = jj ^ sw;
                        unsigned p = pk2(Wob[(kb + 2*jq) * 2 + mcol], Wob[(kb + 2*jq + 1) * 2 + mcol]);
                        z[2*jj]   = (short)(p & 0xFFFFu);
                        z[2*jj+1] = (short)(p >> 16);
                    }
                }
                b4[kki] = z;
            }
            f32x4 accL[RT_N];
            #pragma unroll
            for (int rt = 0; rt < RT_N; ++rt) accL[rt] = (f32x4){0.f, 0.f, 0.f, 0.f};
            #pragma unroll
            for (int rt = 0; rt < RT_N; ++rt) {
                short8 a0 = ((const short8*)Xl4)[(rt*8 + wave*2    )*64 + rl];
                accL[rt] = __builtin_amdgcn_mfma_f32_16x16x32_bf16(a0, b4[0], accL[rt], 0, 0, 0);
                short8 a1 = ((const short8*)Xl4)[(rt*8 + wave*2 + 1)*64 + rl];
                accL[rt] = __builtin_amdgcn_mfma_f32_16x16x32_bf16(a1, b4[1], accL[rt], 0, 0, 0);
            }
            __syncthreads();                     // X dead; overlay partials
            float* part = (float*)Xl4;           // 768 floats
            if (mcol < 2) {
                #pragma unroll
                for (int rt = 0; rt < RT_N; ++rt)
                    #pragma unroll
                    for (int r = 0; r < 4; ++r)
                        part[((rt*16 + quad*4 + r)*2 + mcol)*4 + wave] = accL[rt][r];
            }
            __syncthreads();
            float* res = part + 768;             // 192 floats
            if (tid < 192) {
                float4 p4 = ((const float4*)part)[tid];
                res[tid] = p4.x + p4.y + p4.z + p4.w;
            }
            __syncthreads();
            if (tid < MS) {
                int g = tid >> 4, row = tid & 15;
                // res index: ((st*2+g)*16 + row)*2 + m
                int base = (g * 16 + row) * 2;
                float SH0 = res[base], SH1 = res[base + 1];
                float SA0 = res[base + 64], SA1 = res[base + 65];   // st=1: +2*16*2
                float SB0 = res[base + 128], SB1 = res[base + 129]; // st=2
                float pre0 = SH0 + bob[0], pre1 = SH1 + bob[1];
                bool  m0 = pre0 > 0.f,     m1 = pre1 > 0.f;
                float gx0 = m0 ? pre0 : 0.f, gx1 = m1 ? pre1 : 0.f;
                float J00 = m0 ? SA0 : 0.f;
                float J01 = m0 ? SB0 : 0.f;
                float J10 = m1 ? SA1 : 0.f;
                float J11 = m1 ? SB1 : 0.f;
                float v0 = vbuf[tid*2+0], v1 = vbuf[tid*2+1];
                float w0 = v0, w1 = v1, ld = 0.f;
                const float coef[5] = {1.f, -0.5f, 1.f/3.f, -0.25f, 0.2f};
                #pragma unroll
                for (int k = 0; k < 5; ++k) {
                    float nw0 = fmaf(J00, w0, J01 * w1);
                    float nw1 = fmaf(J10, w0, J11 * w1);
                    w0 = nw0; w1 = nw1;
                    ld = fmaf(coef[k], fmaf(w0, v0, w1 * v1), ld);
                }
                zbuf[tid*2+0] += gx0;
                zbuf[tid*2+1] += gx1;
                dlp -= ld;
            }
        }
        __syncthreads();
    }

    if (tid < MS) {
        out[(size_t)(s0+tid)*2+0] = zbuf[tid*2+0];
        out[(size_t)(s0+tid)*2+1] = zbuf[tid*2+1];
        out[(size_t)2*BATCH + s0 + tid] = dlp;
    }
}

extern "C" void kernel_launch(void* const* d_in, const int* in_sizes, int n_in,
                              void* d_out, int out_size, void* d_ws, size_t ws_size,
                              hipStream_t stream) {
    const float* x  = (const float*)d_in[0];
    const float* v  = (const float*)d_in[1];
    const float* Wi = (const float*)d_in[2];
    const float* bi = (const float*)d_in[3];
    const float* Wm = (const float*)d_in[4];
    const float* bm = (const float*)d_in[5];
    const float* Wo = (const float*)d_in[6];
    const float* bo = (const float*)d_in[7];
    unsigned short* Wp = (unsigned short*)d_ws;   // 24*65536*2 = 3 MiB

    int nchunks = NBLK * NMID * 8192;
    pack_w_kernel<<<(nchunks + 255) / 256, 256, 0, stream>>>(Wm, Wp);
    flow_kernel<<<BATCH / MS, NT, 0, stream>>>(x, v, Wi, bi, bm, Wo, bo, Wp, (float*)d_out);
}

// Round 3
// 1195.187 us; speedup vs baseline: 1.3929x; 1.0882x over previous
//
#include <hip/hip_runtime.h>
#include <hip/hip_bf16.h>

#define BATCH 131072
#define H 256
#define NBLK 8
#define NMID 3
#define MS 32            // samples per workgroup
#define RT_N 6           // (3 streams * MS) / 16 row-tiles
#define NT 512           // threads per workgroup (8 waves, 2 col-tiles each)

typedef __attribute__((ext_vector_type(8))) short short8;   // 8 bf16 = 4 VGPRs (MFMA A/B frag)
typedef __attribute__((ext_vector_type(4))) float f32x4;    // MFMA C/D frag

// pack two f32 -> two bf16 (round-half-up) in 3 VALU ops: 2 adds + v_perm.
// low16 = bf(a), high16 = bf(b)  (matches (bf(a) | bf(b)<<16))
__device__ __forceinline__ unsigned pk2(float a, float b) {
    unsigned ua = __float_as_uint(a) + 0x8000u;
    unsigned ub = __float_as_uint(b) + 0x8000u;
    return __builtin_amdgcn_perm(ub, ua, 0x07060302u);
}

// Pack Wm into MFMA B-frag order bf16 with COLUMN-PERMUTED tiles:
// tile T covers physical cols n = (T>>2)*64 + m*4 + (T&3), m = lane&15.
// => epilogue lanes own consecutive physical columns.
__global__ void pack_w_kernel(const float* __restrict__ Wm, unsigned short* __restrict__ Wp) {
    int o = blockIdx.x * blockDim.x + threadIdx.x;   // 24 * 8192 chunks
    if (o >= NBLK * NMID * 8192) return;
    int lane  = o & 63;
    int T     = (o >> 6) & 15;
    int kk    = (o >> 10) & 7;
    int layer = o >> 13;
    int n  = (T >> 2) * 64 + (lane & 15) * 4 + (T & 3);
    int k0 = kk * 32 + (lane >> 4) * 8;
    const float* src = Wm + (size_t)layer * H * H;
    unsigned int w[4];
    #pragma unroll
    for (int jj = 0; jj < 4; ++jj)
        w[jj] = pk2(src[(size_t)(k0 + 2*jj) * H + n], src[(size_t)(k0 + 2*jj + 1) * H + n]);
    uint4 val; val.x = w[0]; val.y = w[1]; val.z = w[2]; val.w = w[3];
    ((uint4*)Wp)[o] = val;
}

// bias+ReLU on primal, mask tangents, write next layer's A-frag X.
// 8-wave variant: wave owns tiles T=2*wave, 2*wave+1 -> lane owns 2
// consecutive physical cols C, C+1 -> one uint (2 bf16) store per stream.
__device__ __forceinline__ void epilogue_write(const f32x4 (&acc)[RT_N][2],
                                               const float* __restrict__ bias,
                                               unsigned short* __restrict__ Xs,
                                               int wave, int lane) {
    const int mcol = lane & 15, quad = lane >> 4;
    const int C  = (wave >> 1) * 64 + mcol * 4 + ((wave & 1) << 1);  // 2 consecutive cols
    const float b0 = bias[C], b1 = bias[C + 1];
    const int kkx = C >> 5;
    const int qx  = (C >> 3) & 3;
    const int jb  = C & 7;                         // 0,2,4,6
    #pragma unroll
    for (int g = 0; g < 2; ++g) {
        #pragma unroll
        for (int r = 0; r < 4; ++r) {
            float pre0 = acc[g][0][r] + b0;
            float pre1 = acc[g][1][r] + b1;
            bool m0 = pre0 > 0.0f, m1 = pre1 > 0.0f;
            float h0 = m0 ? pre0 : 0.0f,          h1 = m1 ? pre1 : 0.0f;
            float a0 = m0 ? acc[2+g][0][r] : 0.0f, a1 = m1 ? acc[2+g][1][r] : 0.0f;
            float t0 = m0 ? acc[4+g][0][r] : 0.0f, t1 = m1 ? acc[4+g][1][r] : 0.0f;
            int rowm = quad * 4 + r;
            int le   = qx * 16 + rowm;
            int scl  = le ^ ((le >> 3) & 7);
            int e0   = (((g * 8 + kkx) * 64 + scl) * 8) + jb;
            *(unsigned*)(Xs + e0)          = pk2(h0, h1);
            *(unsigned*)(Xs + e0 + 8192)   = pk2(a0, a1);   // ta rows: rt offset +2
            *(unsigned*)(Xs + e0 + 16384)  = pk2(t0, t1);   // tb rows: rt offset +4
        }
    }
}

__global__ __launch_bounds__(NT, 4)   // 4 waves/SIMD => 2 WGs/CU, VGPR cap 128
void flow_kernel(const float* __restrict__ x, const float* __restrict__ v,
                 const float* __restrict__ Wi, const float* __restrict__ bi,
                 const float* __restrict__ bm, const float* __restrict__ Wo,
                 const float* __restrict__ bo,
                 const unsigned short* __restrict__ Wp,
                 float* __restrict__ out)
{
    __shared__ uint4 Xl4[RT_N * 8 * 64];     // 3072 chunks * 16B = 48 KiB
    __shared__ float zbuf[MS * 2];
    __shared__ float vbuf[MS * 2];

    unsigned short* Xs = (unsigned short*)Xl4;

    const int tid  = threadIdx.x;
    const int wave = tid >> 6;
    const int lane = tid & 63;
    const int mcol = lane & 15;
    const int quad = lane >> 4;
    const int s0   = blockIdx.x * MS;
    const int rl   = lane ^ ((lane >> 3) & 7);   // swizzled A-read slot

    float dlp = 0.0f;
    if (tid < MS) {
        zbuf[tid*2+0] = x[(size_t)(s0+tid)*2+0];
        zbuf[tid*2+1] = x[(size_t)(s0+tid)*2+1];
        vbuf[tid*2+0] = v[(size_t)(s0+tid)*2+0];
        vbuf[tid*2+1] = v[(size_t)(s0+tid)*2+1];
    }
    __syncthreads();

    for (int b = 0; b < NBLK; ++b) {
        // ------------- layer 0: 2 -> 256 via MFMA (K padded to 32) -------------
        // Fill X0: 384 chunks; only q==0,j<2 nonzero.
        if (tid < 384) {
            int rt = tid >> 6, cl = tid & 63;
            int l = cl ^ ((cl >> 3) & 7);
            int m = l & 15, q = l >> 4;
            int st = rt >> 1;
            uint4 pk = {0u, 0u, 0u, 0u};
            if (q == 0) {
                if (st == 0) {
                    int s = ((rt & 1) << 4) | m;
                    pk.x = pk2(zbuf[s*2+0], zbuf[s*2+1]);
                } else if (st == 1) pk.x = 0x00003F80u;   // (1,0)
                else                pk.x = 0x3F800000u;   // (0,1)
            }
            Xl4[rt * 512 + cl] = pk;
        }
        __syncthreads();

        const float* Wi0 = Wi + (size_t)b * 2 * H;
        const float* Wi1 = Wi0 + H;
        {
            short8 b0f[2];
            #pragma unroll
            for (int ct = 0; ct < 2; ++ct) {
                short8 z = {0,0,0,0,0,0,0,0};
                if (lane < 16) {
                    int n = (wave >> 1) * 64 + lane * 4 + ((wave & 1) << 1) + ct;
                    unsigned p = pk2(Wi0[n], Wi1[n]);
                    z[0] = (short)(p & 0xFFFFu);
                    z[1] = (short)(p >> 16);
                }
                b0f[ct] = z;
            }
            f32x4 acc[RT_N][2];
            #pragma unroll
            for (int rt = 0; rt < RT_N; ++rt)
                #pragma unroll
                for (int ct = 0; ct < 2; ++ct)
                    acc[rt][ct] = (f32x4){0.f, 0.f, 0.f, 0.f};
            #pragma unroll
            for (int rt = 0; rt < RT_N; ++rt) {
                short8 af = ((const short8*)Xl4)[(rt * 8) * 64 + rl];
                #pragma unroll
                for (int ct = 0; ct < 2; ++ct)
                    acc[rt][ct] = __builtin_amdgcn_mfma_f32_16x16x32_bf16(af, b0f[ct], acc[rt][ct], 0, 0, 0);
            }
            __syncthreads();                     // X0 reads done
            epilogue_write(acc, bi + (size_t)b * H, Xs, wave, lane);
            __syncthreads();
        }

        // ------------- mid layers: 3x (256 -> 256) via MFMA -------------
        for (int li = 0; li < NMID; ++li) {
            const int layer = b * NMID + li;
            const short8* Bp  = ((const short8*)Wp) + (size_t)layer * 8192;
            const float* bias = bm + (size_t)layer * H;

            f32x4 acc[RT_N][2];
            #pragma unroll
            for (int rt = 0; rt < RT_N; ++rt)
                #pragma unroll
                for (int ct = 0; ct < 2; ++ct)
                    acc[rt][ct] = (f32x4){0.f, 0.f, 0.f, 0.f};

            #pragma unroll 2
            for (int kk = 0; kk < 8; ++kk) {
                short8 bf[2];
                #pragma unroll
                for (int ct = 0; ct < 2; ++ct)
                    bf[ct] = Bp[(kk*16 + wave*2 + ct)*64 + lane];        // coalesced b128 (L2-hot)
                #pragma unroll
                for (int rt = 0; rt < RT_N; ++rt) {
                    short8 af = ((const short8*)Xl4)[(rt*8 + kk)*64 + rl]; // ds_read_b128
                    #pragma unroll
                    for (int ct = 0; ct < 2; ++ct)
                        acc[rt][ct] = __builtin_amdgcn_mfma_f32_16x16x32_bf16(af, bf[ct], acc[rt][ct], 0, 0, 0);
                }
            }
            __syncthreads();                     // all waves done reading X
            epilogue_write(acc, bias, Xs, wave, lane);
            __syncthreads();
        }

        // ------------- layer 4: 256 -> 2 via MFMA (N padded to 16) -------------
        const float* Wob = Wo + (size_t)b * H * 2;
        const float* bob = bo + (size_t)b * 2;
        {
            short8 b4 = {0,0,0,0,0,0,0,0};
            if (mcol < 2) {
                int kb = wave * 32 + quad * 8;   // wave owns one kk (K=32) slice
                #pragma unroll
                for (int jj = 0; jj < 4; ++jj) {
                    unsigned p = pk2(Wob[(kb + 2*jj) * 2 + mcol], Wob[(kb + 2*jj + 1) * 2 + mcol]);
                    b4[2*jj]   = (short)(p & 0xFFFFu);
                    b4[2*jj+1] = (short)(p >> 16);
                }
            }
            f32x4 accL[RT_N];
            #pragma unroll
            for (int rt = 0; rt < RT_N; ++rt) accL[rt] = (f32x4){0.f, 0.f, 0.f, 0.f};
            #pragma unroll
            for (int rt = 0; rt < RT_N; ++rt) {
                short8 a0 = ((const short8*)Xl4)[(rt*8 + wave)*64 + rl];
                accL[rt] = __builtin_amdgcn_mfma_f32_16x16x32_bf16(a0, b4, accL[rt], 0, 0, 0);
            }
            __syncthreads();                     // X dead; overlay partials
            float* part = (float*)Xl4;           // 1536 floats
            if (mcol < 2) {
                #pragma unroll
                for (int rt = 0; rt < RT_N; ++rt)
                    #pragma unroll
                    for (int r = 0; r < 4; ++r)
                        part[((rt*16 + quad*4 + r)*2 + mcol)*8 + wave] = accL[rt][r];
            }
            __syncthreads();
            float* res = part + 1536;            // 192 floats
            if (tid < 192) {
                float4 p4 = ((const float4*)part)[tid*2];
                float4 q4 = ((const float4*)part)[tid*2 + 1];
                res[tid] = (p4.x + p4.y + p4.z + p4.w) + (q4.x + q4.y + q4.z + q4.w);
            }
            __syncthreads();
            if (tid < MS) {
                int g = tid >> 4, row = tid & 15;
                // res index: ((st*2+g)*16 + row)*2 + m
                int base = (g * 16 + row) * 2;
                float SH0 = res[base], SH1 = res[base + 1];
                float SA0 = res[base + 64], SA1 = res[base + 65];   // st=1: +2*16*2
                float SB0 = res[base + 128], SB1 = res[base + 129]; // st=2
                float pre0 = SH0 + bob[0], pre1 = SH1 + bob[1];
                bool  m0 = pre0 > 0.f,     m1 = pre1 > 0.f;
                float gx0 = m0 ? pre0 : 0.f, gx1 = m1 ? pre1 : 0.f;
                float J00 = m0 ? SA0 : 0.f;
                float J01 = m0 ? SB0 : 0.f;
                float J10 = m1 ? SA1 : 0.f;
                float J11 = m1 ? SB1 : 0.f;
                float v0 = vbuf[tid*2+0], v1 = vbuf[tid*2+1];
                float w0 = v0, w1 = v1, ld = 0.f;
                const float coef[5] = {1.f, -0.5f, 1.f/3.f, -0.25f, 0.2f};
                #pragma unroll
                for (int k = 0; k < 5; ++k) {
                    float nw0 = fmaf(J00, w0, J01 * w1);
                    float nw1 = fmaf(J10, w0, J11 * w1);
                    w0 = nw0; w1 = nw1;
                    ld = fmaf(coef[k], fmaf(w0, v0, w1 * v1), ld);
                }
                zbuf[tid*2+0] += gx0;
                zbuf[tid*2+1] += gx1;
                dlp -= ld;
            }
        }
        __syncthreads();
    }

    if (tid < MS) {
        out[(size_t)(s0+tid)*2+0] = zbuf[tid*2+0];
        out[(size_t)(s0+tid)*2+1] = zbuf[tid*2+1];
        out[(size_t)2*BATCH + s0 + tid] = dlp;
    }
}

extern "C" void kernel_launch(void* const* d_in, const int* in_sizes, int n_in,
                              void* d_out, int out_size, void* d_ws, size_t ws_size,
                              hipStream_t stream) {
    const float* x  = (const float*)d_in[0];
    const float* v  = (const float*)d_in[1];
    const float* Wi = (const float*)d_in[2];
    const float* bi = (const float*)d_in[3];
    const float* Wm = (const float*)d_in[4];
    const float* bm = (const float*)d_in[5];
    const float* Wo = (const float*)d_in[6];
    const float* bo = (const float*)d_in[7];
    unsigned short* Wp = (unsigned short*)d_ws;   // 24*65536*2 = 3 MiB

    int nchunks = NBLK * NMID * 8192;
    pack_w_kernel<<<(nchunks + 255) / 256, 256, 0, stream>>>(Wm, Wp);
    flow_kernel<<<BATCH / MS, NT, 0, stream>>>(x, v, Wi, bi, bm, Wo, bo, Wp, (float*)d_out);
}

// Round 5
// 1189.603 us; speedup vs baseline: 1.3994x; 1.0047x over previous
//
#include <hip/hip_runtime.h>
#include <hip/hip_bf16.h>

#define BATCH 131072
#define H 256
#define NBLK 8
#define NMID 3
#define MS 32            // samples per workgroup
#define RT_N 6           // (3 streams * MS) / 16 row-tiles
#define NT 512           // threads per workgroup (8 waves = 2 row-groups x 4 col-groups)

typedef __attribute__((ext_vector_type(8))) short short8;   // 8 bf16 = 4 VGPRs (MFMA A/B frag)
typedef __attribute__((ext_vector_type(4))) float f32x4;    // MFMA C/D frag

// pack two f32 -> two bf16 (round-half-up) in 3 VALU ops: 2 adds + v_perm.
// low16 = bf(a), high16 = bf(b)  (matches (bf(a) | bf(b)<<16))
__device__ __forceinline__ unsigned pk2(float a, float b) {
    unsigned ua = __float_as_uint(a) + 0x8000u;
    unsigned ub = __float_as_uint(b) + 0x8000u;
    return __builtin_amdgcn_perm(ub, ua, 0x07060302u);
}

// Pack Wm into MFMA B-frag order bf16 with COLUMN-PERMUTED tiles:
// tile T covers physical cols n = (T>>2)*64 + m*4 + (T&3), m = lane&15.
// => epilogue lanes own 4 consecutive physical columns (one uint2 store).
__global__ void pack_w_kernel(const float* __restrict__ Wm, unsigned short* __restrict__ Wp) {
    int o = blockIdx.x * blockDim.x + threadIdx.x;   // 24 * 8192 chunks
    if (o >= NBLK * NMID * 8192) return;
    int lane  = o & 63;
    int T     = (o >> 6) & 15;
    int kk    = (o >> 10) & 7;
    int layer = o >> 13;
    int n  = (T >> 2) * 64 + (lane & 15) * 4 + (T & 3);
    int k0 = kk * 32 + (lane >> 4) * 8;
    const float* src = Wm + (size_t)layer * H * H;
    unsigned int w[4];
    #pragma unroll
    for (int jj = 0; jj < 4; ++jj)
        w[jj] = pk2(src[(size_t)(k0 + 2*jj) * H + n], src[(size_t)(k0 + 2*jj + 1) * H + n]);
    uint4 val; val.x = w[0]; val.y = w[1]; val.z = w[2]; val.w = w[3];
    ((uint4*)Wp)[o] = val;
}

// bias+ReLU on primal, mask tangents, write next layer's A-frag X.
// Wave (rg,cg): owns rt {rg,2+rg,4+rg} x tiles {cg*4..cg*4+3} -> lane owns 4
// consecutive cols -> one uint2 per stream per r.
// kk-parity slot swizzle (scl ^= kkx&1) makes the per-quad write banks a
// bijection over (qx, mcol>>3) -> conflict-free b64 stores. Readers xor kk&1.
__device__ __forceinline__ void epilogue_write(const f32x4 (&acc)[3][4],
                                               const float* __restrict__ bias,
                                               unsigned short* __restrict__ Xs,
                                               int rg, int cg, int lane) {
    const int mcol = lane & 15, quad = lane >> 4;
    const int nb = cg * 64 + mcol * 4;             // 4 consecutive output cols
    const float4 bv = *(const float4*)(bias + nb);
    const int kkx = nb >> 5;
    const int qx  = (nb >> 3) & 3;
    const int jb  = nb & 7;                        // 0 or 4
    const int kx1 = kkx & 1;
    #pragma unroll
    for (int r = 0; r < 4; ++r) {
        float pre[4], hv[4], ta[4], tb[4];
        pre[0] = acc[0][0][r] + bv.x; pre[1] = acc[0][1][r] + bv.y;
        pre[2] = acc[0][2][r] + bv.z; pre[3] = acc[0][3][r] + bv.w;
        #pragma unroll
        for (int c = 0; c < 4; ++c) {
            bool mk = pre[c] > 0.0f;
            hv[c] = mk ? pre[c]      : 0.0f;
            ta[c] = mk ? acc[1][c][r] : 0.0f;
            tb[c] = mk ? acc[2][c][r] : 0.0f;
        }
        int rowm = quad * 4 + r;
        int le   = qx * 16 + rowm;
        int scl  = (le ^ ((le >> 3) & 7)) ^ kx1;
        int e0   = (((rg * 8 + kkx) * 64 + scl) * 8) + jb;
        uint2 ph; ph.x = pk2(hv[0], hv[1]); ph.y = pk2(hv[2], hv[3]);
        uint2 pa; pa.x = pk2(ta[0], ta[1]); pa.y = pk2(ta[2], ta[3]);
        uint2 pb; pb.x = pk2(tb[0], tb[1]); pb.y = pk2(tb[2], tb[3]);
        *(uint2*)(Xs + e0)          = ph;
        *(uint2*)(Xs + e0 + 8192)   = pa;   // ta rows: rt offset +2 => +2*8*64*8 elems
        *(uint2*)(Xs + e0 + 16384)  = pb;   // tb rows: rt offset +4
    }
}

__global__ __launch_bounds__(NT, 4)   // 4 waves/SIMD => 2 WGs/CU, VGPR cap 128
void flow_kernel(const float* __restrict__ x, const float* __restrict__ v,
                 const float* __restrict__ Wi, const float* __restrict__ bi,
                 const float* __restrict__ bm, const float* __restrict__ Wo,
                 const float* __restrict__ bo,
                 const unsigned short* __restrict__ Wp,
                 float* __restrict__ out)
{
    __shared__ uint4 Xl4[RT_N * 8 * 64];     // 3072 chunks * 16B = 48 KiB
    __shared__ float zbuf[MS * 2];
    __shared__ float vbuf[MS * 2];

    unsigned short* Xs = (unsigned short*)Xl4;

    const int tid  = threadIdx.x;
    const int wave = tid >> 6;
    const int lane = tid & 63;
    const int mcol = lane & 15;
    const int quad = lane >> 4;
    const int rg   = wave >> 2;                  // row-group: rt {rg, 2+rg, 4+rg}
    const int cg   = wave & 3;                   // col-group: tiles {cg*4 .. cg*4+3}
    const int s0   = blockIdx.x * MS;
    const int rl   = lane ^ ((lane >> 3) & 7);   // swizzled A-read slot (xor kk&1 per-read)

    float dlp = 0.0f;
    if (tid < MS) {
        zbuf[tid*2+0] = x[(size_t)(s0+tid)*2+0];
        zbuf[tid*2+1] = x[(size_t)(s0+tid)*2+1];
        vbuf[tid*2+0] = v[(size_t)(s0+tid)*2+0];
        vbuf[tid*2+1] = v[(size_t)(s0+tid)*2+1];
    }
    __syncthreads();

    for (int b = 0; b < NBLK; ++b) {
        // ------------- layer 0: 2 -> 256 via MFMA (K padded to 32) -------------
        // Fill X0: 384 chunks (kk=0 only -> no slot xor); only q==0,j<2 nonzero.
        if (tid < 384) {
            int rt = tid >> 6, cl = tid & 63;
            int l = cl ^ ((cl >> 3) & 7);
            int m = l & 15, q = l >> 4;
            int st = rt >> 1;
            uint4 pk = {0u, 0u, 0u, 0u};
            if (q == 0) {
                if (st == 0) {
                    int s = ((rt & 1) << 4) | m;
                    pk.x = pk2(zbuf[s*2+0], zbuf[s*2+1]);
                } else if (st == 1) pk.x = 0x00003F80u;   // (1,0)
                else                pk.x = 0x3F800000u;   // (0,1)
            }
            Xl4[rt * 512 + cl] = pk;
        }
        __syncthreads();

        const float* Wi0 = Wi + (size_t)b * 2 * H;
        const float* Wi1 = Wi0 + H;
        {
            short8 b0f[4];
            #pragma unroll
            for (int ct = 0; ct < 4; ++ct) {
                short8 z = {0,0,0,0,0,0,0,0};
                if (lane < 16) {
                    int n = cg * 64 + lane * 4 + ct;
                    unsigned p = pk2(Wi0[n], Wi1[n]);
                    z[0] = (short)(p & 0xFFFFu);
                    z[1] = (short)(p >> 16);
                }
                b0f[ct] = z;
            }
            f32x4 acc[3][4];
            #pragma unroll
            for (int st = 0; st < 3; ++st)
                #pragma unroll
                for (int ct = 0; ct < 4; ++ct)
                    acc[st][ct] = (f32x4){0.f, 0.f, 0.f, 0.f};
            #pragma unroll
            for (int st = 0; st < 3; ++st) {
                int rt = st * 2 + rg;
                short8 af = ((const short8*)Xl4)[(rt * 8) * 64 + rl];
                #pragma unroll
                for (int ct = 0; ct < 4; ++ct)
                    acc[st][ct] = __builtin_amdgcn_mfma_f32_16x16x32_bf16(af, b0f[ct], acc[st][ct], 0, 0, 0);
            }
            __syncthreads();                     // X0 reads done
            epilogue_write(acc, bi + (size_t)b * H, Xs, rg, cg, lane);
            __syncthreads();
        }

        // ------------- mid layers: 3x (256 -> 256) via MFMA -------------
        for (int li = 0; li < NMID; ++li) {
            const int layer = b * NMID + li;
            const short8* Bp  = ((const short8*)Wp) + (size_t)layer * 8192;
            const float* bias = bm + (size_t)layer * H;

            f32x4 acc[3][4];
            #pragma unroll
            for (int st = 0; st < 3; ++st)
                #pragma unroll
                for (int ct = 0; ct < 4; ++ct)
                    acc[st][ct] = (f32x4){0.f, 0.f, 0.f, 0.f};

            #pragma unroll 2
            for (int kk = 0; kk < 8; ++kk) {
                short8 bf[4];
                #pragma unroll
                for (int ct = 0; ct < 4; ++ct)
                    bf[ct] = Bp[(kk*16 + cg*4 + ct)*64 + lane];      // coalesced b128 (L2-hot)
                const int rls = rl ^ (kk & 1);
                #pragma unroll
                for (int st = 0; st < 3; ++st) {
                    int rt = st * 2 + rg;
                    short8 af = ((const short8*)Xl4)[(rt*8 + kk)*64 + rls]; // ds_read_b128
                    #pragma unroll
                    for (int ct = 0; ct < 4; ++ct)
                        acc[st][ct] = __builtin_amdgcn_mfma_f32_16x16x32_bf16(af, bf[ct], acc[st][ct], 0, 0, 0);
                }
            }
            __syncthreads();                     // all waves done reading X
            epilogue_write(acc, bias, Xs, rg, cg, lane);
            __syncthreads();
        }

        // ------------- layer 4: 256 -> 2 via MFMA (N padded to 16) -------------
        const float* Wob = Wo + (size_t)b * H * 2;
        const float* bob = bo + (size_t)b * 2;
        {
            short8 b4 = {0,0,0,0,0,0,0,0};
            if (mcol < 2) {
                int kb = wave * 32 + quad * 8;   // wave owns one kk (K=32) slice
                #pragma unroll
                for (int jj = 0; jj < 4; ++jj) {
                    unsigned p = pk2(Wob[(kb + 2*jj) * 2 + mcol], Wob[(kb + 2*jj + 1) * 2 + mcol]);
                    b4[2*jj]   = (short)(p & 0xFFFFu);
                    b4[2*jj+1] = (short)(p >> 16);
                }
            }
            f32x4 accL[RT_N];
            #pragma unroll
            for (int rt = 0; rt < RT_N; ++rt) accL[rt] = (f32x4){0.f, 0.f, 0.f, 0.f};
            const int rls = rl ^ (wave & 1);     // chunks at kk=wave carry kk-parity swizzle
            #pragma unroll
            for (int rt = 0; rt < RT_N; ++rt) {
                short8 a0 = ((const short8*)Xl4)[(rt*8 + wave)*64 + rls];
                accL[rt] = __builtin_amdgcn_mfma_f32_16x16x32_bf16(a0, b4, accL[rt], 0, 0, 0);
            }
            __syncthreads();                     // X dead; overlay partials
            float* part = (float*)Xl4;           // 1536 floats
            if (mcol < 2) {
                #pragma unroll
                for (int rt = 0; rt < RT_N; ++rt)
                    #pragma unroll
                    for (int r = 0; r < 4; ++r)
                        part[((rt*16 + quad*4 + r)*2 + mcol)*8 + wave] = accL[rt][r];
            }
            __syncthreads();
            float* res = part + 1536;            // 192 floats
            if (tid < 192) {
                float4 p4 = ((const float4*)part)[tid*2];
                float4 q4 = ((const float4*)part)[tid*2 + 1];
                res[tid] = (p4.x + p4.y + p4.z + p4.w) + (q4.x + q4.y + q4.z + q4.w);
            }
            __syncthreads();
            if (tid < MS) {
                int g = tid >> 4, row = tid & 15;
                // res index: ((st*2+g)*16 + row)*2 + m
                int base = (g * 16 + row) * 2;
                float SH0 = res[base], SH1 = res[base + 1];
                float SA0 = res[base + 64], SA1 = res[base + 65];   // st=1: +2*16*2
                float SB0 = res[base + 128], SB1 = res[base + 129]; // st=2
                float pre0 = SH0 + bob[0], pre1 = SH1 + bob[1];
                bool  m0 = pre0 > 0.f,     m1 = pre1 > 0.f;
                float gx0 = m0 ? pre0 : 0.f, gx1 = m1 ? pre1 : 0.f;
                float J00 = m0 ? SA0 : 0.f;
                float J01 = m0 ? SB0 : 0.f;
                float J10 = m1 ? SA1 : 0.f;
                float J11 = m1 ? SB1 : 0.f;
                float v0 = vbuf[tid*2+0], v1 = vbuf[tid*2+1];
                float w0 = v0, w1 = v1, ld = 0.f;
                const float coef[5] = {1.f, -0.5f, 1.f/3.f, -0.25f, 0.2f};
                #pragma unroll
                for (int k = 0; k < 5; ++k) {
                    float nw0 = fmaf(J00, w0, J01 * w1);
                    float nw1 = fmaf(J10, w0, J11 * w1);
                    w0 = nw0; w1 = nw1;
                    ld = fmaf(coef[k], fmaf(w0, v0, w1 * v1), ld);
                }
                zbuf[tid*2+0] += gx0;
                zbuf[tid*2+1] += gx1;
                dlp -= ld;
            }
        }
        __syncthreads();
    }

    if (tid < MS) {
        out[(size_t)(s0+tid)*2+0] = zbuf[tid*2+0];
        out[(size_t)(s0+tid)*2+1] = zbuf[tid*2+1];
        out[(size_t)2*BATCH + s0 + tid] = dlp;
    }
}

extern "C" void kernel_launch(void* const* d_in, const int* in_sizes, int n_in,
                              void* d_out, int out_size, void* d_ws, size_t ws_size,
                              hipStream_t stream) {
    const float* x  = (const float*)d_in[0];
    const float* v  = (const float*)d_in[1];
    const float* Wi = (const float*)d_in[2];
    const float* bi = (const float*)d_in[3];
    const float* Wm = (const float*)d_in[4];
    const float* bm = (const float*)d_in[5];
    const float* Wo = (const float*)d_in[6];
    const float* bo = (const float*)d_in[7];
    unsigned short* Wp = (unsigned short*)d_ws;   // 24*65536*2 = 3 MiB

    int nchunks = NBLK * NMID * 8192;
    pack_w_kernel<<<(nchunks + 255) / 256, 256, 0, stream>>>(Wm, Wp);
    flow_kernel<<<BATCH / MS, NT, 0, stream>>>(x, v, Wi, bi, bm, Wo, bo, Wp, (float*)d_out);
}

// Round 6
// 1186.268 us; speedup vs baseline: 1.4034x; 1.0028x over previous
//
#include <hip/hip_runtime.h>
#include <hip/hip_bf16.h>

#define BATCH 131072
#define H 256
#define NBLK 8
#define NMID 3
#define MS 16            // samples per workgroup (split along the rg independence line)
#define RT_N 3           // 3 streams * 16 rows / 16 = 3 row-tiles
#define NT 256           // 4 waves; each wave owns one 64-col group (cg)

typedef __attribute__((ext_vector_type(8))) short short8;   // 8 bf16 = 4 VGPRs (MFMA A/B frag)
typedef __attribute__((ext_vector_type(4))) float f32x4;    // MFMA C/D frag

// pack two f32 -> two bf16 (round-half-up): 2 adds + v_perm. Used on cold paths.
__device__ __forceinline__ unsigned pk2(float a, float b) {
    unsigned ua = __float_as_uint(a) + 0x8000u;
    unsigned ub = __float_as_uint(b) + 0x8000u;
    return __builtin_amdgcn_perm(ub, ua, 0x07060302u);
}
// hot-path pack: single-instruction RNE pack (low16 = bf(a), high16 = bf(b))
__device__ __forceinline__ unsigned cpk(float a, float b) {
    unsigned r;
    asm("v_cvt_pk_bf16_f32 %0, %1, %2" : "=v"(r) : "v"(a), "v"(b));
    return r;
}

// Pack Wm into MFMA B-frag order bf16 with COLUMN-PERMUTED tiles:
// tile T covers physical cols n = (T>>2)*64 + m*4 + (T&3), m = lane&15.
// => epilogue lanes own 4 consecutive physical columns (one uint2 store).
__global__ void pack_w_kernel(const float* __restrict__ Wm, unsigned short* __restrict__ Wp) {
    int o = blockIdx.x * blockDim.x + threadIdx.x;   // 24 * 8192 chunks
    if (o >= NBLK * NMID * 8192) return;
    int lane  = o & 63;
    int T     = (o >> 6) & 15;
    int kk    = (o >> 10) & 7;
    int layer = o >> 13;
    int n  = (T >> 2) * 64 + (lane & 15) * 4 + (T & 3);
    int k0 = kk * 32 + (lane >> 4) * 8;
    const float* src = Wm + (size_t)layer * H * H;
    unsigned int w[4];
    #pragma unroll
    for (int jj = 0; jj < 4; ++jj)
        w[jj] = pk2(src[(size_t)(k0 + 2*jj) * H + n], src[(size_t)(k0 + 2*jj + 1) * H + n]);
    uint4 val; val.x = w[0]; val.y = w[1]; val.z = w[2]; val.w = w[3];
    ((uint4*)Wp)[o] = val;
}

// ReLU on primal (bias already in acc[0] via C-init), mask tangents, write
// next layer's A-frag X. Wave cg owns tiles {cg*4..cg*4+3} -> lane owns 4
// consecutive cols. kk-parity slot swizzle (scl ^= kkx&1): conflict-free b64
// stores; readers xor kk&1.
__device__ __forceinline__ void epilogue_write(const f32x4 (&acc)[RT_N][4],
                                               unsigned short* __restrict__ Xs,
                                               int cg, int lane) {
    const int mcol = lane & 15, quad = lane >> 4;
    const int nb  = cg * 64 + mcol * 4;            // 4 consecutive output cols
    const int kkx = nb >> 5;
    const int qx  = (nb >> 3) & 3;
    const int jb  = nb & 7;                        // 0 or 4
    const int kx1 = kkx & 1;
    #pragma unroll
    for (int r = 0; r < 4; ++r) {
        float hv[4], ta[4], tb[4];
        #pragma unroll
        for (int c = 0; c < 4; ++c) {
            float pre = acc[0][c][r];              // bias carried by acc init
            bool mk = pre > 0.0f;
            hv[c] = fmaxf(pre, 0.0f);
            ta[c] = mk ? acc[1][c][r] : 0.0f;
            tb[c] = mk ? acc[2][c][r] : 0.0f;
        }
        int le  = qx * 16 + quad * 4 + r;
        int scl = (le ^ ((le >> 3) & 7)) ^ kx1;
        int e0  = ((kkx * 64 + scl) * 8) + jb;     // rt=0 (primal) chunk base
        uint2 ph; ph.x = cpk(hv[0], hv[1]); ph.y = cpk(hv[2], hv[3]);
        uint2 pa; pa.x = cpk(ta[0], ta[1]); pa.y = cpk(ta[2], ta[3]);
        uint2 pb; pb.x = cpk(tb[0], tb[1]); pb.y = cpk(tb[2], tb[3]);
        *(uint2*)(Xs + e0)         = ph;
        *(uint2*)(Xs + e0 + 4096)  = pa;   // ta rows: rt 1 => +8*64*8 shorts
        *(uint2*)(Xs + e0 + 8192)  = pb;   // tb rows: rt 2
    }
}

__global__ __launch_bounds__(NT, 4)   // 4 waves/SIMD => 4 WGs/CU, VGPR cap 128
void flow_kernel(const float* __restrict__ x, const float* __restrict__ v,
                 const float* __restrict__ Wi, const float* __restrict__ bi,
                 const float* __restrict__ bm, const float* __restrict__ Wo,
                 const float* __restrict__ bo,
                 const unsigned short* __restrict__ Wp,
                 float* __restrict__ out)
{
    __shared__ uint4 Xl4[RT_N * 8 * 64];     // 1536 chunks * 16B = 24 KiB
    __shared__ float zbuf[MS * 2];
    __shared__ float vbuf[MS * 2];

    unsigned short* Xs = (unsigned short*)Xl4;

    const int tid  = threadIdx.x;
    const int cg   = tid >> 6;                   // wave = col-group {cg*4 .. cg*4+3}
    const int lane = tid & 63;
    const int mcol = lane & 15;
    const int quad = lane >> 4;
    const int s0   = blockIdx.x * MS;
    const int rl   = lane ^ ((lane >> 3) & 7);   // swizzled A-read slot (xor kk&1 per-read)

    float dlp = 0.0f;
    if (tid < MS) {
        zbuf[tid*2+0] = x[(size_t)(s0+tid)*2+0];
        zbuf[tid*2+1] = x[(size_t)(s0+tid)*2+1];
        vbuf[tid*2+0] = v[(size_t)(s0+tid)*2+0];
        vbuf[tid*2+1] = v[(size_t)(s0+tid)*2+1];
    }
    __syncthreads();

    for (int b = 0; b < NBLK; ++b) {
        // ------------- layer 0: 2 -> 256 via MFMA (K padded to 32) -------------
        // Fill X0: 192 chunks (kk=0 -> no parity xor); only q==0, j<2 nonzero.
        if (tid < 192) {
            int st = tid >> 6, cl = tid & 63;
            int l = cl ^ ((cl >> 3) & 7);
            int m = l & 15, q = l >> 4;
            uint4 pk = {0u, 0u, 0u, 0u};
            if (q == 0) {
                if (st == 0)      pk.x = pk2(zbuf[m*2+0], zbuf[m*2+1]);
                else if (st == 1) pk.x = 0x00003F80u;   // (1,0)
                else              pk.x = 0x3F800000u;   // (0,1)
            }
            Xl4[st * 512 + cl] = pk;
        }
        __syncthreads();

        const float* Wi0 = Wi + (size_t)b * 2 * H;
        const float* Wi1 = Wi0 + H;
        {
            short8 b0f[4];
            #pragma unroll
            for (int ct = 0; ct < 4; ++ct) {
                short8 z = {0,0,0,0,0,0,0,0};
                if (lane < 16) {
                    int n = cg * 64 + lane * 4 + ct;
                    unsigned p = pk2(Wi0[n], Wi1[n]);
                    z[0] = (short)(p & 0xFFFFu);
                    z[1] = (short)(p >> 16);
                }
                b0f[ct] = z;
            }
            const float4 bv = *(const float4*)(bi + (size_t)b * H + cg * 64 + mcol * 4);
            f32x4 acc[RT_N][4];
            #pragma unroll
            for (int ct = 0; ct < 4; ++ct) {
                float bb = (ct == 0) ? bv.x : (ct == 1) ? bv.y : (ct == 2) ? bv.z : bv.w;
                acc[0][ct] = (f32x4){bb, bb, bb, bb};   // bias via C-operand
                acc[1][ct] = (f32x4){0.f, 0.f, 0.f, 0.f};
                acc[2][ct] = (f32x4){0.f, 0.f, 0.f, 0.f};
            }
            #pragma unroll
            for (int st = 0; st < RT_N; ++st) {
                short8 af = ((const short8*)Xl4)[(st * 8) * 64 + rl];
                #pragma unroll
                for (int ct = 0; ct < 4; ++ct)
                    acc[st][ct] = __builtin_amdgcn_mfma_f32_16x16x32_bf16(af, b0f[ct], acc[st][ct], 0, 0, 0);
            }
            __syncthreads();                     // X0 reads done
            epilogue_write(acc, Xs, cg, lane);
            __syncthreads();
        }

        // ------------- mid layers: 3x (256 -> 256) via MFMA -------------
        for (int li = 0; li < NMID; ++li) {
            const int layer = b * NMID + li;
            const short8* Bp  = ((const short8*)Wp) + (size_t)layer * 8192;
            const float* bias = bm + (size_t)layer * H;

            const float4 bv = *(const float4*)(bias + cg * 64 + mcol * 4);
            f32x4 acc[RT_N][4];
            #pragma unroll
            for (int ct = 0; ct < 4; ++ct) {
                float bb = (ct == 0) ? bv.x : (ct == 1) ? bv.y : (ct == 2) ? bv.z : bv.w;
                acc[0][ct] = (f32x4){bb, bb, bb, bb};   // bias via C-operand
                acc[1][ct] = (f32x4){0.f, 0.f, 0.f, 0.f};
                acc[2][ct] = (f32x4){0.f, 0.f, 0.f, 0.f};
            }

            #pragma unroll 2
            for (int kk = 0; kk < 8; ++kk) {
                short8 bf[4];
                #pragma unroll
                for (int ct = 0; ct < 4; ++ct)
                    bf[ct] = Bp[(kk*16 + cg*4 + ct)*64 + lane];      // coalesced b128 (L2-hot)
                const int rls = rl ^ (kk & 1);
                #pragma unroll
                for (int st = 0; st < RT_N; ++st) {
                    short8 af = ((const short8*)Xl4)[(st*8 + kk)*64 + rls]; // ds_read_b128
                    #pragma unroll
                    for (int ct = 0; ct < 4; ++ct)
                        acc[st][ct] = __builtin_amdgcn_mfma_f32_16x16x32_bf16(af, bf[ct], acc[st][ct], 0, 0, 0);
                }
            }
            __syncthreads();                     // all waves done reading X
            epilogue_write(acc, Xs, cg, lane);
            __syncthreads();
        }

        // ------------- layer 4: 256 -> 2 via MFMA (N padded to 16) -------------
        const float* Wob = Wo + (size_t)b * H * 2;
        const float* bob = bo + (size_t)b * 2;
        {
            short8 b4[2];
            #pragma unroll
            for (int kki = 0; kki < 2; ++kki) {
                short8 z = {0,0,0,0,0,0,0,0};
                if (mcol < 2) {
                    int kb = (cg * 2 + kki) * 32 + quad * 8;   // wave owns 2 kk slices
                    #pragma unroll
                    for (int jj = 0; jj < 4; ++jj) {
                        unsigned p = pk2(Wob[(kb + 2*jj) * 2 + mcol], Wob[(kb + 2*jj + 1) * 2 + mcol]);
                        z[2*jj]   = (short)(p & 0xFFFFu);
                        z[2*jj+1] = (short)(p >> 16);
                    }
                }
                b4[kki] = z;
            }
            f32x4 accL[RT_N];
            #pragma unroll
            for (int st = 0; st < RT_N; ++st) accL[st] = (f32x4){0.f, 0.f, 0.f, 0.f};
            #pragma unroll
            for (int kki = 0; kki < 2; ++kki) {
                const int rls = rl ^ (kki & 1);  // chunk kk=cg*2+kki: parity = kki&1
                #pragma unroll
                for (int st = 0; st < RT_N; ++st) {
                    short8 a0 = ((const short8*)Xl4)[(st*8 + cg*2 + kki)*64 + rls];
                    accL[st] = __builtin_amdgcn_mfma_f32_16x16x32_bf16(a0, b4[kki], accL[st], 0, 0, 0);
                }
            }
            __syncthreads();                     // X dead; overlay partials
            float* part = (float*)Xl4;           // 384 floats
            if (mcol < 2) {
                #pragma unroll
                for (int st = 0; st < RT_N; ++st)
                    #pragma unroll
                    for (int r = 0; r < 4; ++r)
                        part[((st*16 + quad*4 + r)*2 + mcol)*4 + cg] = accL[st][r];
            }
            __syncthreads();
            float* res = part + 384;             // 96 floats
            if (tid < 96) {
                float4 p4 = ((const float4*)part)[tid];
                res[tid] = p4.x + p4.y + p4.z + p4.w;
            }
            __syncthreads();
            if (tid < MS) {
                int base = tid * 2;
                float SH0 = res[base],      SH1 = res[base + 1];
                float SA0 = res[base + 32], SA1 = res[base + 33];   // st=1: +16*2
                float SB0 = res[base + 64], SB1 = res[base + 65];   // st=2
                float pre0 = SH0 + bob[0], pre1 = SH1 + bob[1];
                bool  m0 = pre0 > 0.f,     m1 = pre1 > 0.f;
                float gx0 = m0 ? pre0 : 0.f, gx1 = m1 ? pre1 : 0.f;
                float J00 = m0 ? SA0 : 0.f;
                float J01 = m0 ? SB0 : 0.f;
                float J10 = m1 ? SA1 : 0.f;
                float J11 = m1 ? SB1 : 0.f;
                float v0 = vbuf[tid*2+0], v1 = vbuf[tid*2+1];
                float w0 = v0, w1 = v1, ld = 0.f;
                const float coef[5] = {1.f, -0.5f, 1.f/3.f, -0.25f, 0.2f};
                #pragma unroll
                for (int k = 0; k < 5; ++k) {
                    float nw0 = fmaf(J00, w0, J01 * w1);
                    float nw1 = fmaf(J10, w0, J11 * w1);
                    w0 = nw0; w1 = nw1;
                    ld = fmaf(coef[k], fmaf(w0, v0, w1 * v1), ld);
                }
                zbuf[tid*2+0] += gx0;
                zbuf[tid*2+1] += gx1;
                dlp -= ld;
            }
        }
        __syncthreads();
    }

    if (tid < MS) {
        out[(size_t)(s0+tid)*2+0] = zbuf[tid*2+0];
        out[(size_t)(s0+tid)*2+1] = zbuf[tid*2+1];
        out[(size_t)2*BATCH + s0 + tid] = dlp;
    }
}

extern "C" void kernel_launch(void* const* d_in, const int* in_sizes, int n_in,
                              void* d_out, int out_size, void* d_ws, size_t ws_size,
                              hipStream_t stream) {
    const float* x  = (const float*)d_in[0];
    const float* v  = (const float*)d_in[1];
    const float* Wi = (const float*)d_in[2];
    const float* bi = (const float*)d_in[3];
    const float* Wm = (const float*)d_in[4];
    const float* bm = (const float*)d_in[5];
    const float* Wo = (const float*)d_in[6];
    const float* bo = (const float*)d_in[7];
    unsigned short* Wp = (unsigned short*)d_ws;   // 24*65536*2 = 3 MiB

    int nchunks = NBLK * NMID * 8192;
    pack_w_kernel<<<(nchunks + 255) / 256, 256, 0, stream>>>(Wm, Wp);
    flow_kernel<<<BATCH / MS, NT, 0, stream>>>(x, v, Wi, bi, bm, Wo, bo, Wp, (float*)d_out);
}

// Round 7
// 1155.066 us; speedup vs baseline: 1.4413x; 1.0270x over previous
//
#include <hip/hip_runtime.h>
#include <hip/hip_bf16.h>

#define BATCH 131072
#define H 256
#define NBLK 8
#define NMID 3
#define MS 16            // samples per workgroup (split along the rg independence line)
#define RT_N 3           // 3 streams * 16 rows / 16 = 3 row-tiles
#define NT 256           // 4 waves; each wave owns one 64-col group (cg)

typedef __attribute__((ext_vector_type(8))) short short8;   // 8 bf16 = 4 VGPRs (MFMA A/B frag)
typedef __attribute__((ext_vector_type(4))) float f32x4;    // MFMA C/D frag

// pack two f32 -> two bf16 (round-half-up): 2 adds + v_perm. Used on cold paths.
__device__ __forceinline__ unsigned pk2(float a, float b) {
    unsigned ua = __float_as_uint(a) + 0x8000u;
    unsigned ub = __float_as_uint(b) + 0x8000u;
    return __builtin_amdgcn_perm(ub, ua, 0x07060302u);
}
// hot-path pack: single-instruction RNE pack (low16 = bf(a), high16 = bf(b))
__device__ __forceinline__ unsigned cpk(float a, float b) {
    unsigned r;
    asm("v_cvt_pk_bf16_f32 %0, %1, %2" : "=v"(r) : "v"(a), "v"(b));
    return r;
}

// Pack Wm into MFMA B-frag order bf16 with COLUMN-PERMUTED tiles:
// tile T covers physical cols n = (T>>2)*64 + m*4 + (T&3), m = lane&15.
// => epilogue lanes own 4 consecutive physical columns (one uint2 store).
__global__ void pack_w_kernel(const float* __restrict__ Wm, unsigned short* __restrict__ Wp) {
    int o = blockIdx.x * blockDim.x + threadIdx.x;   // 24 * 8192 chunks
    if (o >= NBLK * NMID * 8192) return;
    int lane  = o & 63;
    int T     = (o >> 6) & 15;
    int kk    = (o >> 10) & 7;
    int layer = o >> 13;
    int n  = (T >> 2) * 64 + (lane & 15) * 4 + (T & 3);
    int k0 = kk * 32 + (lane >> 4) * 8;
    const float* src = Wm + (size_t)layer * H * H;
    unsigned int w[4];
    #pragma unroll
    for (int jj = 0; jj < 4; ++jj)
        w[jj] = pk2(src[(size_t)(k0 + 2*jj) * H + n], src[(size_t)(k0 + 2*jj + 1) * H + n]);
    uint4 val; val.x = w[0]; val.y = w[1]; val.z = w[2]; val.w = w[3];
    ((uint4*)Wp)[o] = val;
}

// ReLU on primal (bias already in acc[0] via C-init), mask tangents, write
// next layer's A-frag X. Wave cg owns tiles {cg*4..cg*4+3} -> lane owns 4
// consecutive cols. kk-parity slot swizzle (scl ^= kkx&1): conflict-free b64
// stores; readers xor kk&1.
__device__ __forceinline__ void epilogue_write(const f32x4 (&acc)[RT_N][4],
                                               unsigned short* __restrict__ Xs,
                                               int cg, int lane) {
    const int mcol = lane & 15, quad = lane >> 4;
    const int nb  = cg * 64 + mcol * 4;            // 4 consecutive output cols
    const int kkx = nb >> 5;
    const int qx  = (nb >> 3) & 3;
    const int jb  = nb & 7;                        // 0 or 4
    const int kx1 = kkx & 1;
    #pragma unroll
    for (int r = 0; r < 4; ++r) {
        float hv[4], ta[4], tb[4];
        #pragma unroll
        for (int c = 0; c < 4; ++c) {
            float pre = acc[0][c][r];              // bias carried by acc init
            bool mk = pre > 0.0f;
            hv[c] = fmaxf(pre, 0.0f);
            ta[c] = mk ? acc[1][c][r] : 0.0f;
            tb[c] = mk ? acc[2][c][r] : 0.0f;
        }
        int le  = qx * 16 + quad * 4 + r;
        int scl = (le ^ ((le >> 3) & 7)) ^ kx1;
        int e0  = ((kkx * 64 + scl) * 8) + jb;     // rt=0 (primal) chunk base
        uint2 ph; ph.x = cpk(hv[0], hv[1]); ph.y = cpk(hv[2], hv[3]);
        uint2 pa; pa.x = cpk(ta[0], ta[1]); pa.y = cpk(ta[2], ta[3]);
        uint2 pb; pb.x = cpk(tb[0], tb[1]); pb.y = cpk(tb[2], tb[3]);
        *(uint2*)(Xs + e0)         = ph;
        *(uint2*)(Xs + e0 + 4096)  = pa;   // ta rows: rt 1 => +8*64*8 shorts
        *(uint2*)(Xs + e0 + 8192)  = pb;   // tb rows: rt 2
    }
}

__global__ __launch_bounds__(NT, 4)   // 4 waves/SIMD => 4 WGs/CU, VGPR cap 128
void flow_kernel(const float* __restrict__ x, const float* __restrict__ v,
                 const float* __restrict__ Wi, const float* __restrict__ bi,
                 const float* __restrict__ bm, const float* __restrict__ Wo,
                 const float* __restrict__ bo,
                 const unsigned short* __restrict__ Wp,
                 float* __restrict__ out)
{
    __shared__ uint4 Xl4[RT_N * 8 * 64];     // 1536 chunks * 16B = 24 KiB
    __shared__ float zbuf[MS * 2];
    __shared__ float vbuf[MS * 2];

    unsigned short* Xs = (unsigned short*)Xl4;

    const int tid  = threadIdx.x;
    const int cg   = tid >> 6;                   // wave = col-group {cg*4 .. cg*4+3}
    const int lane = tid & 63;
    const int mcol = lane & 15;
    const int quad = lane >> 4;
    const int s0   = blockIdx.x * MS;
    const int rl   = lane ^ ((lane >> 3) & 7);   // swizzled A-read slot (xor kk&1 per-read)

    float dlp = 0.0f;
    if (tid < MS) {
        zbuf[tid*2+0] = x[(size_t)(s0+tid)*2+0];
        zbuf[tid*2+1] = x[(size_t)(s0+tid)*2+1];
        vbuf[tid*2+0] = v[(size_t)(s0+tid)*2+0];
        vbuf[tid*2+1] = v[(size_t)(s0+tid)*2+1];
    }

    // Phase-stagger co-resident WGs. Round-6 counters: MfmaUtil 52 + VALUBusy 45
    // = 97% with wall == sum -> zero cross-wave pipe overlap; co-resident WGs
    // are phase-locked (same start, identical durations). One-time offset of
    // slot*640 cyc (~quarter of the ~2.7K-cyc layer period) decorrelates them;
    // equal durations then preserve the offset for the rest of the kernel.
    {
        const int slot = (blockIdx.x >> 8) & 3;
        for (int i = 0; i < slot; ++i) __builtin_amdgcn_s_sleep(10);
    }
    __syncthreads();

    for (int b = 0; b < NBLK; ++b) {
        // ------------- layer 0: 2 -> 256 via MFMA (K padded to 32) -------------
        // Fill X0: 192 chunks (kk=0 -> no parity xor); only q==0, j<2 nonzero.
        if (tid < 192) {
            int st = tid >> 6, cl = tid & 63;
            int l = cl ^ ((cl >> 3) & 7);
            int m = l & 15, q = l >> 4;
            uint4 pk = {0u, 0u, 0u, 0u};
            if (q == 0) {
                if (st == 0)      pk.x = pk2(zbuf[m*2+0], zbuf[m*2+1]);
                else if (st == 1) pk.x = 0x00003F80u;   // (1,0)
                else              pk.x = 0x3F800000u;   // (0,1)
            }
            Xl4[st * 512 + cl] = pk;
        }
        __syncthreads();

        const float* Wi0 = Wi + (size_t)b * 2 * H;
        const float* Wi1 = Wi0 + H;
        {
            short8 b0f[4];
            #pragma unroll
            for (int ct = 0; ct < 4; ++ct) {
                short8 z = {0,0,0,0,0,0,0,0};
                if (lane < 16) {
                    int n = cg * 64 + lane * 4 + ct;
                    unsigned p = pk2(Wi0[n], Wi1[n]);
                    z[0] = (short)(p & 0xFFFFu);
                    z[1] = (short)(p >> 16);
                }
                b0f[ct] = z;
            }
            const float4 bv = *(const float4*)(bi + (size_t)b * H + cg * 64 + mcol * 4);
            f32x4 acc[RT_N][4];
            #pragma unroll
            for (int ct = 0; ct < 4; ++ct) {
                float bb = (ct == 0) ? bv.x : (ct == 1) ? bv.y : (ct == 2) ? bv.z : bv.w;
                acc[0][ct] = (f32x4){bb, bb, bb, bb};   // bias via C-operand
                acc[1][ct] = (f32x4){0.f, 0.f, 0.f, 0.f};
                acc[2][ct] = (f32x4){0.f, 0.f, 0.f, 0.f};
            }
            #pragma unroll
            for (int st = 0; st < RT_N; ++st) {
                short8 af = ((const short8*)Xl4)[(st * 8) * 64 + rl];
                #pragma unroll
                for (int ct = 0; ct < 4; ++ct)
                    acc[st][ct] = __builtin_amdgcn_mfma_f32_16x16x32_bf16(af, b0f[ct], acc[st][ct], 0, 0, 0);
            }
            __syncthreads();                     // X0 reads done
            epilogue_write(acc, Xs, cg, lane);
            __syncthreads();
        }

        // ------------- mid layers: 3x (256 -> 256) via MFMA -------------
        for (int li = 0; li < NMID; ++li) {
            const int layer = b * NMID + li;
            const short8* Bp  = ((const short8*)Wp) + (size_t)layer * 8192;
            const float* bias = bm + (size_t)layer * H;

            const float4 bv = *(const float4*)(bias + cg * 64 + mcol * 4);
            f32x4 acc[RT_N][4];
            #pragma unroll
            for (int ct = 0; ct < 4; ++ct) {
                float bb = (ct == 0) ? bv.x : (ct == 1) ? bv.y : (ct == 2) ? bv.z : bv.w;
                acc[0][ct] = (f32x4){bb, bb, bb, bb};   // bias via C-operand
                acc[1][ct] = (f32x4){0.f, 0.f, 0.f, 0.f};
                acc[2][ct] = (f32x4){0.f, 0.f, 0.f, 0.f};
            }

            #pragma unroll 2
            for (int kk = 0; kk < 8; ++kk) {
                short8 bf[4];
                #pragma unroll
                for (int ct = 0; ct < 4; ++ct)
                    bf[ct] = Bp[(kk*16 + cg*4 + ct)*64 + lane];      // coalesced b128 (L2-hot)
                const int rls = rl ^ (kk & 1);
                #pragma unroll
                for (int st = 0; st < RT_N; ++st) {
                    short8 af = ((const short8*)Xl4)[(st*8 + kk)*64 + rls]; // ds_read_b128
                    #pragma unroll
                    for (int ct = 0; ct < 4; ++ct)
                        acc[st][ct] = __builtin_amdgcn_mfma_f32_16x16x32_bf16(af, bf[ct], acc[st][ct], 0, 0, 0);
                }
            }
            __syncthreads();                     // all waves done reading X
            epilogue_write(acc, Xs, cg, lane);
            __syncthreads();
        }

        // ------------- layer 4: 256 -> 2 via MFMA (N padded to 16) -------------
        const float* Wob = Wo + (size_t)b * H * 2;
        const float* bob = bo + (size_t)b * 2;
        {
            short8 b4[2];
            #pragma unroll
            for (int kki = 0; kki < 2; ++kki) {
                short8 z = {0,0,0,0,0,0,0,0};
                if (mcol < 2) {
                    int kb = (cg * 2 + kki) * 32 + quad * 8;   // wave owns 2 kk slices
                    #pragma unroll
                    for (int jj = 0; jj < 4; ++jj) {
                        unsigned p = pk2(Wob[(kb + 2*jj) * 2 + mcol], Wob[(kb + 2*jj + 1) * 2 + mcol]);
                        z[2*jj]   = (short)(p & 0xFFFFu);
                        z[2*jj+1] = (short)(p >> 16);
                    }
                }
                b4[kki] = z;
            }
            f32x4 accL[RT_N];
            #pragma unroll
            for (int st = 0; st < RT_N; ++st) accL[st] = (f32x4){0.f, 0.f, 0.f, 0.f};
            #pragma unroll
            for (int kki = 0; kki < 2; ++kki) {
                const int rls = rl ^ (kki & 1);  // chunk kk=cg*2+kki: parity = kki&1
                #pragma unroll
                for (int st = 0; st < RT_N; ++st) {
                    short8 a0 = ((const short8*)Xl4)[(st*8 + cg*2 + kki)*64 + rls];
                    accL[st] = __builtin_amdgcn_mfma_f32_16x16x32_bf16(a0, b4[kki], accL[st], 0, 0, 0);
                }
            }
            __syncthreads();                     // X dead; overlay partials
            float* part = (float*)Xl4;           // 384 floats
            if (mcol < 2) {
                #pragma unroll
                for (int st = 0; st < RT_N; ++st)
                    #pragma unroll
                    for (int r = 0; r < 4; ++r)
                        part[((st*16 + quad*4 + r)*2 + mcol)*4 + cg] = accL[st][r];
            }
            __syncthreads();
            float* res = part + 384;             // 96 floats
            if (tid < 96) {
                float4 p4 = ((const float4*)part)[tid];
                res[tid] = p4.x + p4.y + p4.z + p4.w;
            }
            __syncthreads();
            if (tid < MS) {
                int base = tid * 2;
                float SH0 = res[base],      SH1 = res[base + 1];
                float SA0 = res[base + 32], SA1 = res[base + 33];   // st=1: +16*2
                float SB0 = res[base + 64], SB1 = res[base + 65];   // st=2
                float pre0 = SH0 + bob[0], pre1 = SH1 + bob[1];
                bool  m0 = pre0 > 0.f,     m1 = pre1 > 0.f;
                float gx0 = m0 ? pre0 : 0.f, gx1 = m1 ? pre1 : 0.f;
                float J00 = m0 ? SA0 : 0.f;
                float J01 = m0 ? SB0 : 0.f;
                float J10 = m1 ? SA1 : 0.f;
                float J11 = m1 ? SB1 : 0.f;
                float v0 = vbuf[tid*2+0], v1 = vbuf[tid*2+1];
                float w0 = v0, w1 = v1, ld = 0.f;
                const float coef[5] = {1.f, -0.5f, 1.f/3.f, -0.25f, 0.2f};
                #pragma unroll
                for (int k = 0; k < 5; ++k) {
                    float nw0 = fmaf(J00, w0, J01 * w1);
                    float nw1 = fmaf(J10, w0, J11 * w1);
                    w0 = nw0; w1 = nw1;
                    ld = fmaf(coef[k], fmaf(w0, v0, w1 * v1), ld);
                }
                zbuf[tid*2+0] += gx0;
                zbuf[tid*2+1] += gx1;
                dlp -= ld;
            }
        }
        __syncthreads();
    }

    if (tid < MS) {
        out[(size_t)(s0+tid)*2+0] = zbuf[tid*2+0];
        out[(size_t)(s0+tid)*2+1] = zbuf[tid*2+1];
        out[(size_t)2*BATCH + s0 + tid] = dlp;
    }
}

extern "C" void kernel_launch(void* const* d_in, const int* in_sizes, int n_in,
                              void* d_out, int out_size, void* d_ws, size_t ws_size,
                              hipStream_t stream) {
    const float* x  = (const float*)d_in[0];
    const float* v  = (const float*)d_in[1];
    const float* Wi = (const float*)d_in[2];
    const float* bi = (const float*)d_in[3];
    const float* Wm = (const float*)d_in[4];
    const float* bm = (const float*)d_in[5];
    const float* Wo = (const float*)d_in[6];
    const float* bo = (const float*)d_in[7];
    unsigned short* Wp = (unsigned short*)d_ws;   // 24*65536*2 = 3 MiB

    int nchunks = NBLK * NMID * 8192;
    pack_w_kernel<<<(nchunks + 255) / 256, 256, 0, stream>>>(Wm, Wp);
    flow_kernel<<<BATCH / MS, NT, 0, stream>>>(x, v, Wi, bi, bm, Wo, bo, Wp, (float*)d_out);
}